// Round 1
// baseline (1295.426 us; speedup 1.0000x reference)
//
#include <hip/hip_runtime.h>
#include <hip/hip_bf16.h>

#define NN 50000
#define EE 400000
#define PP 3
// H=4, D=32, IN=128, HD=128

__device__ __forceinline__ float eluf(float v) {
    return v > 0.f ? v : (expf(v) - 1.f);
}

// ---------------- K1: feature attention -> x[N,128] ----------------
// block = 256 threads = 16 nodes x 16 lanes
__global__ __launch_bounds__(256) void k_featattn(
    const float* __restrict__ h, const float* __restrict__ c,
    const float* __restrict__ w1, const float* __restrict__ b1,
    const float* __restrict__ w2, float* __restrict__ x)
{
    __shared__ float sC[16 * 840];
    __shared__ float sW1[42 * 16];
    __shared__ float sB1[16];
    __shared__ float sW2[16];
    const int tid = threadIdx.x;
    const int n0 = blockIdx.x * 16;

    for (int i = tid; i < 672; i += 256) sW1[i] = w1[i];
    if (tid < 16) { sB1[tid] = b1[tid]; sW2[tid] = w2[tid]; }

    const float4* c4 = (const float4*)(c + (size_t)n0 * 840);
    float4* sC4 = (float4*)sC;
    for (int i = tid; i < 3360; i += 256) sC4[i] = c4[i];
    __syncthreads();

    const int j  = tid & 15;
    const int nn = tid >> 4;
    const float* myC = sC + nn * 840;
    const float bj = sB1[j], w2j = sW2[j];

    float part[20];
    for (int r = 0; r < 20; ++r) {
        float acc = bj;
        const float* row = myC + r * 42;
        #pragma unroll
        for (int i = 0; i < 42; ++i) acc += row[i] * sW1[i * 16 + j];
        part[r] = tanhf(acc) * w2j;
    }
    #pragma unroll
    for (int r = 0; r < 20; ++r) {
        float v = part[r];
        v += __shfl_xor(v, 1);
        v += __shfl_xor(v, 2);
        v += __shfl_xor(v, 4);
        v += __shfl_xor(v, 8);
        part[r] = v;
    }
    float m = part[0];
    #pragma unroll
    for (int r = 1; r < 20; ++r) m = fmaxf(m, part[r]);
    float s = 0.f;
    #pragma unroll
    for (int r = 0; r < 20; ++r) { part[r] = expf(part[r] - m); s += part[r]; }
    const float inv = 1.f / s;

    float e0 = 0.f, e1 = 0.f, e2 = 0.f;
    #pragma unroll
    for (int r = 0; r < 20; ++r) {
        const float b = part[r] * inv;
        const float* row = myC + r * 42;
        e0 += b * row[j];
        e1 += b * row[j + 16];
        if (j < 10) e2 += b * row[j + 32];
    }
    const int n = n0 + nn;
    float* xr = x + (size_t)n * 128;
    xr[86 + j]      = e0;
    xr[86 + j + 16] = e1;
    if (j < 10) xr[86 + j + 32] = e2;

    // copy h into x[:, :86]
    for (int i = tid; i < 16 * 86; i += 256) {
        const int node = i / 86, col = i % 86;
        x[(size_t)(n0 + node) * 128 + col] = h[(size_t)(n0 + node) * 86 + col];
    }
}

// ---------------- K2: feat = x @ W_p, plus el/er epilogue ----------------
// grid (ceil(N/64), P), block 256; 64 rows x 128 cols per block
__global__ __launch_bounds__(256) void k_gat_gemm(
    const float* __restrict__ x, const float* __restrict__ W,
    const float* __restrict__ attn_l, const float* __restrict__ attn_r,
    float* __restrict__ feat, float* __restrict__ el, float* __restrict__ er)
{
    __shared__ float sX[64 * 128];
    const int tid = threadIdx.x;
    const int p  = blockIdx.y;
    const int n0 = blockIdx.x * 64;

    float4* sX4 = (float4*)sX;
    for (int i = tid; i < 2048; i += 256) {
        const int row = i >> 5, c4 = i & 31;
        float4 v = make_float4(0.f, 0.f, 0.f, 0.f);
        if (n0 + row < NN) v = ((const float4*)(x + (size_t)(n0 + row) * 128))[c4];
        sX4[i] = v;
    }
    __syncthreads();

    const int tc = tid & 31;   // 4-col group
    const int tr = tid >> 5;   // 8-row group
    const float* Wp = W + (size_t)p * 128 * 128;

    float acc[8][4];
    for (int r = 0; r < 8; ++r)
        for (int q = 0; q < 4; ++q) acc[r][q] = 0.f;

    #pragma unroll 4
    for (int k = 0; k < 128; ++k) {
        const float4 wv = ((const float4*)(Wp + k * 128))[tc];
        #pragma unroll
        for (int r = 0; r < 8; ++r) {
            const float xv = sX[(tr * 8 + r) * 128 + k];
            acc[r][0] += xv * wv.x;
            acc[r][1] += xv * wv.y;
            acc[r][2] += xv * wv.z;
            acc[r][3] += xv * wv.w;
        }
    }

    float al[4], ar[4];
    {
        const float* alp = attn_l + p * 128 + tc * 4;
        const float* arp = attn_r + p * 128 + tc * 4;
        for (int q = 0; q < 4; ++q) { al[q] = alp[q]; ar[q] = arp[q]; }
    }
    const int hh = tc >> 3;
    for (int r = 0; r < 8; ++r) {
        const int n = n0 + tr * 8 + r;
        const bool ok = n < NN;
        if (ok) {
            const float4 v = make_float4(acc[r][0], acc[r][1], acc[r][2], acc[r][3]);
            ((float4*)(feat + (size_t)(p * NN + n) * 128))[tc] = v;
        }
        float pl = acc[r][0]*al[0] + acc[r][1]*al[1] + acc[r][2]*al[2] + acc[r][3]*al[3];
        float pr = acc[r][0]*ar[0] + acc[r][1]*ar[1] + acc[r][2]*ar[2] + acc[r][3]*ar[3];
        pl += __shfl_xor(pl, 1); pl += __shfl_xor(pl, 2); pl += __shfl_xor(pl, 4);
        pr += __shfl_xor(pr, 1); pr += __shfl_xor(pr, 2); pr += __shfl_xor(pr, 4);
        if (ok && (tc & 7) == 0) {
            el[(size_t)(p * NN + n) * 4 + hh] = pl;
            er[(size_t)(p * NN + n) * 4 + hh] = pr;
        }
    }
}

// ---------------- K3: per-edge exp(leaky(el[s]+er[d])), denom atomics -----
__global__ __launch_bounds__(256) void k_edge1(
    const int* __restrict__ src, const int* __restrict__ dst,
    const float* __restrict__ el, const float* __restrict__ er,
    float* __restrict__ ee, float* __restrict__ zsum)
{
    const int p = blockIdx.y;
    const int e = blockIdx.x * 256 + threadIdx.x;
    if (e >= EE) return;
    const int s = src[p * EE + e];
    const int d = dst[p * EE + e];
    const float4 a = ((const float4*)el)[p * NN + s];
    const float4 b = ((const float4*)er)[p * NN + d];
    float v[4] = {a.x + b.x, a.y + b.y, a.z + b.z, a.w + b.w};
    float o[4];
    #pragma unroll
    for (int h = 0; h < 4; ++h) {
        float t = v[h] > 0.f ? v[h] : 0.2f * v[h];
        t = expf(t);
        o[h] = t;
        atomicAdd(&zsum[(size_t)(p * NN + d) * 4 + h], t);
    }
    ((float4*)ee)[p * EE + e] = make_float4(o[0], o[1], o[2], o[3]);
}

// ---------------- K4: aggregation, one wave per edge ----------------
__global__ __launch_bounds__(256) void k_edge2(
    const int* __restrict__ src, const int* __restrict__ dst,
    const float* __restrict__ ee, const float* __restrict__ zsum,
    const float* __restrict__ feat, float* __restrict__ agg)
{
    const int p = blockIdx.y;
    const int w = threadIdx.x >> 6;
    const int lane = threadIdx.x & 63;
    const int e = blockIdx.x * 4 + w;
    if (e >= EE) return;
    const int s = src[p * EE + e];
    const int d = dst[p * EE + e];
    const float4 eev = ((const float4*)ee)[p * EE + e];
    const float4 zv  = ((const float4*)zsum)[p * NN + d];
    const float a[4] = {eev.x / zv.x, eev.y / zv.y, eev.z / zv.z, eev.w / zv.w};
    const float* fsrc = feat + (size_t)(p * NN + s) * 128;
    float* adst = agg + (size_t)(p * NN + d) * 128;
    const int h0 = lane >> 5;
    const float f0 = fsrc[lane];
    const float f1 = fsrc[lane + 64];
    atomicAdd(&adst[lane],      a[h0]     * f0);
    atomicAdd(&adst[lane + 64], a[2 + h0] * f1);
}

// ---------------- K5: semantic scores wsem[p] = sum_n tanh(z@w1+b1)@w2 ----
__global__ __launch_bounds__(256) void k_sem_score(
    const float* __restrict__ agg, const float* __restrict__ w1,
    const float* __restrict__ b1, const float* __restrict__ w2,
    float* __restrict__ wsem)
{
    __shared__ float sZ[64 * 128];
    __shared__ float sPart[8];
    const int tid = threadIdx.x;
    const int p  = blockIdx.y;
    const int n0 = blockIdx.x * 64;

    float4* sZ4 = (float4*)sZ;
    for (int i = tid; i < 2048; i += 256) {
        const int row = i >> 5, c4 = i & 31;
        float4 v = make_float4(0.f, 0.f, 0.f, 0.f);
        if (n0 + row < NN) {
            v = ((const float4*)(agg + (size_t)(p * NN + n0 + row) * 128))[c4];
            v.x = eluf(v.x); v.y = eluf(v.y); v.z = eluf(v.z); v.w = eluf(v.w);
        }
        sZ4[i] = v;
    }
    __syncthreads();

    const int tc = tid & 31;
    const int tr = tid >> 5;

    float acc[8][4];
    for (int r = 0; r < 8; ++r)
        for (int q = 0; q < 4; ++q) acc[r][q] = 0.f;

    #pragma unroll 4
    for (int k = 0; k < 128; ++k) {
        const float4 wv = ((const float4*)(w1 + k * 128))[tc];
        #pragma unroll
        for (int r = 0; r < 8; ++r) {
            const float zv = sZ[(tr * 8 + r) * 128 + k];
            acc[r][0] += zv * wv.x;
            acc[r][1] += zv * wv.y;
            acc[r][2] += zv * wv.z;
            acc[r][3] += zv * wv.w;
        }
    }

    float bb[4], ww[4];
    for (int q = 0; q < 4; ++q) { bb[q] = b1[tc * 4 + q]; ww[q] = w2[tc * 4 + q]; }

    float local = 0.f;
    for (int r = 0; r < 8; ++r) {
        float pr = 0.f;
        for (int q = 0; q < 4; ++q) pr += tanhf(acc[r][q] + bb[q]) * ww[q];
        pr += __shfl_xor(pr, 1);
        pr += __shfl_xor(pr, 2);
        pr += __shfl_xor(pr, 4);
        pr += __shfl_xor(pr, 8);
        pr += __shfl_xor(pr, 16);
        if (tc == 0 && (n0 + tr * 8 + r) < NN) local += pr;
    }
    if (tc == 0) sPart[tr] = local;
    __syncthreads();
    if (tid == 0) {
        float t = 0.f;
        for (int i = 0; i < 8; ++i) t += sPart[i];
        atomicAdd(&wsem[p], t);
    }
}

// ---------------- K6: bsem = softmax(wsem / N) ----------------
__global__ void k_bsem(const float* __restrict__ wsem, float* __restrict__ bsem)
{
    if (threadIdx.x == 0 && blockIdx.x == 0) {
        float w[PP];
        for (int p = 0; p < PP; ++p) w[p] = wsem[p] / (float)NN;
        float m = fmaxf(w[0], fmaxf(w[1], w[2]));
        float s = 0.f;
        for (int p = 0; p < PP; ++p) { w[p] = expf(w[p] - m); s += w[p]; }
        for (int p = 0; p < PP; ++p) bsem[p] = w[p] / s;
    }
}

// ---------------- K7: out = sum_p bsem[p] * elu(agg_p) ----------------
__global__ __launch_bounds__(256) void k_final(
    const float* __restrict__ agg, const float* __restrict__ bsem,
    float* __restrict__ out)
{
    const int i = blockIdx.x * 256 + threadIdx.x;
    if (i >= NN * 128) return;
    const float b0 = bsem[0], b1 = bsem[1], b2 = bsem[2];
    const float v0 = agg[i];
    const float v1 = agg[(size_t)NN * 128 + i];
    const float v2 = agg[(size_t)2 * NN * 128 + i];
    out[i] = b0 * eluf(v0) + b1 * eluf(v1) + b2 * eluf(v2);
}

extern "C" void kernel_launch(void* const* d_in, const int* in_sizes, int n_in,
                              void* d_out, int out_size, void* d_ws, size_t ws_size,
                              hipStream_t stream) {
    const float* h      = (const float*)d_in[0];
    const float* c      = (const float*)d_in[1];
    const float* fa_w1  = (const float*)d_in[2];
    const float* fa_b1  = (const float*)d_in[3];
    const float* fa_w2  = (const float*)d_in[4];
    const float* gat_W  = (const float*)d_in[5];
    const float* attn_l = (const float*)d_in[6];
    const float* attn_r = (const float*)d_in[7];
    const float* sa_w1  = (const float*)d_in[8];
    const float* sa_b1  = (const float*)d_in[9];
    const float* sa_w2  = (const float*)d_in[10];
    const int*   src    = (const int*)d_in[11];
    const int*   dst    = (const int*)d_in[12];
    float* out = (float*)d_out;

    float* ws   = (float*)d_ws;
    float* x    = ws;                  // 6,400,000
    float* feat = x + 6400000;         // 19,200,000
    float* el   = feat + 19200000;     //   600,000
    float* er   = el + 600000;         //   600,000
    float* ee   = er + 600000;         // 4,800,000
    float* agg  = ee + 4800000;        // 19,200,000
    float* zsum = agg + 19200000;      //   600,000
    float* wsem = zsum + 600000;       //         4
    float* bsem = wsem + 4;            //         4

    // zero agg + zsum + wsem in one contiguous memset
    hipMemsetAsync(agg, 0, (size_t)(19200000 + 600000 + 4) * sizeof(float), stream);

    k_featattn<<<NN / 16, 256, 0, stream>>>(h, c, fa_w1, fa_b1, fa_w2, x);
    k_gat_gemm<<<dim3((NN + 63) / 64, PP), 256, 0, stream>>>(x, gat_W, attn_l, attn_r, feat, el, er);
    k_edge1<<<dim3((EE + 255) / 256, PP), 256, 0, stream>>>(src, dst, el, er, ee, zsum);
    k_edge2<<<dim3(EE / 4, PP), 256, 0, stream>>>(src, dst, ee, zsum, feat, agg);
    k_sem_score<<<dim3((NN + 63) / 64, PP), 256, 0, stream>>>(agg, sa_w1, sa_b1, sa_w2, wsem);
    k_bsem<<<1, 64, 0, stream>>>(wsem, bsem);
    k_final<<<(NN * 128 + 255) / 256, 256, 0, stream>>>(agg, bsem, out);
}

// Round 2
// 817.386 us; speedup vs baseline: 1.5848x; 1.5848x over previous
//
#include <hip/hip_runtime.h>
#include <hip/hip_bf16.h>

#define NN 50000
#define EE 400000
#define PP 3
#define NBLK 196   // ceil(NN/256)
// H=4, D=32, IN=128, HD=128

__device__ __forceinline__ float eluf(float v) {
    return v > 0.f ? v : (expf(v) - 1.f);
}

// ---------------- K1: feature attention -> x[N,128] ----------------
// block = 256 threads = 16 nodes x 16 lanes
__global__ __launch_bounds__(256) void k_featattn(
    const float* __restrict__ h, const float* __restrict__ c,
    const float* __restrict__ w1, const float* __restrict__ b1,
    const float* __restrict__ w2, float* __restrict__ x)
{
    __shared__ float sC[16 * 840];
    __shared__ float sW1[42 * 16];
    __shared__ float sB1[16];
    __shared__ float sW2[16];
    const int tid = threadIdx.x;
    const int n0 = blockIdx.x * 16;

    for (int i = tid; i < 672; i += 256) sW1[i] = w1[i];
    if (tid < 16) { sB1[tid] = b1[tid]; sW2[tid] = w2[tid]; }

    const float4* c4 = (const float4*)(c + (size_t)n0 * 840);
    float4* sC4 = (float4*)sC;
    for (int i = tid; i < 3360; i += 256) sC4[i] = c4[i];
    __syncthreads();

    const int j  = tid & 15;
    const int nn = tid >> 4;
    const float* myC = sC + nn * 840;
    const float bj = sB1[j], w2j = sW2[j];

    float part[20];
    for (int r = 0; r < 20; ++r) {
        float acc = bj;
        const float* row = myC + r * 42;
        #pragma unroll
        for (int i = 0; i < 42; ++i) acc += row[i] * sW1[i * 16 + j];
        part[r] = tanhf(acc) * w2j;
    }
    #pragma unroll
    for (int r = 0; r < 20; ++r) {
        float v = part[r];
        v += __shfl_xor(v, 1);
        v += __shfl_xor(v, 2);
        v += __shfl_xor(v, 4);
        v += __shfl_xor(v, 8);
        part[r] = v;
    }
    float m = part[0];
    #pragma unroll
    for (int r = 1; r < 20; ++r) m = fmaxf(m, part[r]);
    float s = 0.f;
    #pragma unroll
    for (int r = 0; r < 20; ++r) { part[r] = expf(part[r] - m); s += part[r]; }
    const float inv = 1.f / s;

    float e0 = 0.f, e1 = 0.f, e2 = 0.f;
    #pragma unroll
    for (int r = 0; r < 20; ++r) {
        const float b = part[r] * inv;
        const float* row = myC + r * 42;
        e0 += b * row[j];
        e1 += b * row[j + 16];
        if (j < 10) e2 += b * row[j + 32];
    }
    const int n = n0 + nn;
    float* xr = x + (size_t)n * 128;
    xr[86 + j]      = e0;
    xr[86 + j + 16] = e1;
    if (j < 10) xr[86 + j + 32] = e2;

    // copy h into x[:, :86]
    for (int i = tid; i < 16 * 86; i += 256) {
        const int node = i / 86, col = i % 86;
        x[(size_t)(n0 + node) * 128 + col] = h[(size_t)(n0 + node) * 86 + col];
    }
}

// ---------------- K2: feat = x @ W_p, plus el/er epilogue ----------------
__global__ __launch_bounds__(256) void k_gat_gemm(
    const float* __restrict__ x, const float* __restrict__ W,
    const float* __restrict__ attn_l, const float* __restrict__ attn_r,
    float* __restrict__ feat, float* __restrict__ el, float* __restrict__ er)
{
    __shared__ float sX[64 * 128];
    const int tid = threadIdx.x;
    const int p  = blockIdx.y;
    const int n0 = blockIdx.x * 64;

    float4* sX4 = (float4*)sX;
    for (int i = tid; i < 2048; i += 256) {
        const int row = i >> 5, c4 = i & 31;
        float4 v = make_float4(0.f, 0.f, 0.f, 0.f);
        if (n0 + row < NN) v = ((const float4*)(x + (size_t)(n0 + row) * 128))[c4];
        sX4[i] = v;
    }
    __syncthreads();

    const int tc = tid & 31;   // 4-col group
    const int tr = tid >> 5;   // 8-row group
    const float* Wp = W + (size_t)p * 128 * 128;

    float acc[8][4];
    for (int r = 0; r < 8; ++r)
        for (int q = 0; q < 4; ++q) acc[r][q] = 0.f;

    #pragma unroll 4
    for (int k = 0; k < 128; ++k) {
        const float4 wv = ((const float4*)(Wp + k * 128))[tc];
        #pragma unroll
        for (int r = 0; r < 8; ++r) {
            const float xv = sX[(tr * 8 + r) * 128 + k];
            acc[r][0] += xv * wv.x;
            acc[r][1] += xv * wv.y;
            acc[r][2] += xv * wv.z;
            acc[r][3] += xv * wv.w;
        }
    }

    float al[4], ar[4];
    {
        const float* alp = attn_l + p * 128 + tc * 4;
        const float* arp = attn_r + p * 128 + tc * 4;
        for (int q = 0; q < 4; ++q) { al[q] = alp[q]; ar[q] = arp[q]; }
    }
    const int hh = tc >> 3;
    for (int r = 0; r < 8; ++r) {
        const int n = n0 + tr * 8 + r;
        const bool ok = n < NN;
        if (ok) {
            const float4 v = make_float4(acc[r][0], acc[r][1], acc[r][2], acc[r][3]);
            ((float4*)(feat + (size_t)(p * NN + n) * 128))[tc] = v;
        }
        float pl = acc[r][0]*al[0] + acc[r][1]*al[1] + acc[r][2]*al[2] + acc[r][3]*al[3];
        float pr = acc[r][0]*ar[0] + acc[r][1]*ar[1] + acc[r][2]*ar[2] + acc[r][3]*ar[3];
        pl += __shfl_xor(pl, 1); pl += __shfl_xor(pl, 2); pl += __shfl_xor(pl, 4);
        pr += __shfl_xor(pr, 1); pr += __shfl_xor(pr, 2); pr += __shfl_xor(pr, 4);
        if (ok && (tc & 7) == 0) {
            el[(size_t)(p * NN + n) * 4 + hh] = pl;
            er[(size_t)(p * NN + n) * 4 + hh] = pr;
        }
    }
}

// ---------------- CSR build: histogram ----------------
__global__ __launch_bounds__(256) void k_hist(
    const int* __restrict__ dst, int* __restrict__ deg)
{
    const int p = blockIdx.y;
    const int e = blockIdx.x * 256 + threadIdx.x;
    if (e < EE) atomicAdd(&deg[p * NN + dst[p * EE + e]], 1);
}

// ---------------- CSR build: per-block partial sums ----------------
__global__ __launch_bounds__(256) void k_partial(
    const int* __restrict__ deg, int* __restrict__ psum)
{
    __shared__ int s[256];
    const int p = blockIdx.y;
    const int i = blockIdx.x * 256 + threadIdx.x;
    s[threadIdx.x] = (i < NN) ? deg[p * NN + i] : 0;
    __syncthreads();
    for (int off = 128; off > 0; off >>= 1) {
        if (threadIdx.x < off) s[threadIdx.x] += s[threadIdx.x + off];
        __syncthreads();
    }
    if (threadIdx.x == 0) psum[p * NBLK + blockIdx.x] = s[0];
}

// ---------------- CSR build: scan block partials (tiny) ----------------
__global__ void k_scanpsum(int* __restrict__ psum)
{
    const int p = blockIdx.x;
    if (threadIdx.x == 0) {
        int run = 0;
        for (int i = 0; i < NBLK; ++i) {
            int t = psum[p * NBLK + i];
            psum[p * NBLK + i] = run;
            run += t;
        }
    }
}

// ---------------- CSR build: final exclusive scan -> row_start, cursor ----
__global__ __launch_bounds__(256) void k_scanfinal(
    const int* __restrict__ deg, const int* __restrict__ psum,
    int* __restrict__ row_start, int* __restrict__ cursor)
{
    __shared__ int s[256];
    const int p = blockIdx.y, t = threadIdx.x;
    const int i = blockIdx.x * 256 + t;
    const int v = (i < NN) ? deg[p * NN + i] : 0;
    s[t] = v;
    __syncthreads();
    for (int off = 1; off < 256; off <<= 1) {
        int xv = 0;
        if (t >= off) xv = s[t - off];
        __syncthreads();
        s[t] += xv;
        __syncthreads();
    }
    const int excl = s[t] - v + psum[p * NBLK + blockIdx.x];
    if (i < NN) {
        row_start[p * (NN + 1) + i] = excl;
        cursor[p * NN + i] = excl;
        if (i == NN - 1) row_start[p * (NN + 1) + NN] = excl + v;
    }
}

// ---------------- scatter: sorted src + per-edge exp(leaky(el+er)) -------
__global__ __launch_bounds__(256) void k_scatter(
    const int* __restrict__ src, const int* __restrict__ dst,
    const float* __restrict__ el, const float* __restrict__ er,
    int* __restrict__ cursor, int* __restrict__ s_src, float* __restrict__ s_ee)
{
    const int p = blockIdx.y;
    const int e = blockIdx.x * 256 + threadIdx.x;
    if (e >= EE) return;
    const int s = src[p * EE + e];
    const int d = dst[p * EE + e];
    const float4 a = ((const float4*)el)[p * NN + s];
    const float4 b = ((const float4*)er)[p * NN + d];
    float4 o;
    {
        float t0 = a.x + b.x, t1 = a.y + b.y, t2 = a.z + b.z, t3 = a.w + b.w;
        t0 = t0 > 0.f ? t0 : 0.2f * t0;
        t1 = t1 > 0.f ? t1 : 0.2f * t1;
        t2 = t2 > 0.f ? t2 : 0.2f * t2;
        t3 = t3 > 0.f ? t3 : 0.2f * t3;
        o = make_float4(expf(t0), expf(t1), expf(t2), expf(t3));
    }
    const int slot = atomicAdd(&cursor[p * NN + d], 1);
    s_src[p * EE + slot] = s;
    ((float4*)s_ee)[p * EE + slot] = o;
}

// ---------------- aggregation: one wave per dst node, no atomics ---------
// z_out = elu( (sum_e ee*feat[src]) / (sum_e ee) )
__global__ __launch_bounds__(256) void k_agg(
    const int* __restrict__ row_start, const int* __restrict__ s_src,
    const float* __restrict__ s_ee, const float* __restrict__ feat,
    float* __restrict__ z)
{
    const int p = blockIdx.y;
    const int w = threadIdx.x >> 6;
    const int lane = threadIdx.x & 63;
    const int n = blockIdx.x * 4 + w;
    if (n >= NN) return;
    const int st = row_start[p * (NN + 1) + n];
    const int en = row_start[p * (NN + 1) + n + 1];

    const bool lo = lane < 32;
    const int* ss = s_src + (size_t)p * EE;
    const float4* ee4 = (const float4*)s_ee + (size_t)p * EE;
    const float* fbase = feat + (size_t)p * NN * 128;

    float acc0 = 0.f, acc1 = 0.f, za = 0.f, zb = 0.f;
    for (int i = st; i < en; ++i) {
        const int sn = ss[i];
        const float4 e4 = ee4[i];
        const float ea = lo ? e4.x : e4.y;
        const float eb = lo ? e4.z : e4.w;
        const float* f = fbase + (size_t)sn * 128;
        acc0 += ea * f[lane];
        acc1 += eb * f[lane + 64];
        za += ea;
        zb += eb;
    }
    float v0 = 0.f, v1 = 0.f;
    if (en > st) { v0 = acc0 / za; v1 = acc1 / zb; }
    v0 = v0 > 0.f ? v0 : (expf(v0) - 1.f);
    v1 = v1 > 0.f ? v1 : (expf(v1) - 1.f);
    const size_t o = (size_t)(p * NN + n) * 128;
    z[o + lane] = v0;
    z[o + 64 + lane] = v1;
}

// ---------------- K5: semantic scores (z already elu'd) ----------------
__global__ __launch_bounds__(256) void k_sem_score(
    const float* __restrict__ z, const float* __restrict__ w1,
    const float* __restrict__ b1, const float* __restrict__ w2,
    float* __restrict__ wsem)
{
    __shared__ float sZ[64 * 128];
    __shared__ float sPart[8];
    const int tid = threadIdx.x;
    const int p  = blockIdx.y;
    const int n0 = blockIdx.x * 64;

    float4* sZ4 = (float4*)sZ;
    for (int i = tid; i < 2048; i += 256) {
        const int row = i >> 5, c4 = i & 31;
        float4 v = make_float4(0.f, 0.f, 0.f, 0.f);
        if (n0 + row < NN)
            v = ((const float4*)(z + (size_t)(p * NN + n0 + row) * 128))[c4];
        sZ4[i] = v;
    }
    __syncthreads();

    const int tc = tid & 31;
    const int tr = tid >> 5;

    float acc[8][4];
    for (int r = 0; r < 8; ++r)
        for (int q = 0; q < 4; ++q) acc[r][q] = 0.f;

    #pragma unroll 4
    for (int k = 0; k < 128; ++k) {
        const float4 wv = ((const float4*)(w1 + k * 128))[tc];
        #pragma unroll
        for (int r = 0; r < 8; ++r) {
            const float zv = sZ[(tr * 8 + r) * 128 + k];
            acc[r][0] += zv * wv.x;
            acc[r][1] += zv * wv.y;
            acc[r][2] += zv * wv.z;
            acc[r][3] += zv * wv.w;
        }
    }

    float bb[4], ww[4];
    for (int q = 0; q < 4; ++q) { bb[q] = b1[tc * 4 + q]; ww[q] = w2[tc * 4 + q]; }

    float local = 0.f;
    for (int r = 0; r < 8; ++r) {
        float pr = 0.f;
        for (int q = 0; q < 4; ++q) pr += tanhf(acc[r][q] + bb[q]) * ww[q];
        pr += __shfl_xor(pr, 1);
        pr += __shfl_xor(pr, 2);
        pr += __shfl_xor(pr, 4);
        pr += __shfl_xor(pr, 8);
        pr += __shfl_xor(pr, 16);
        if (tc == 0 && (n0 + tr * 8 + r) < NN) local += pr;
    }
    if (tc == 0) sPart[tr] = local;
    __syncthreads();
    if (tid == 0) {
        float t = 0.f;
        for (int i = 0; i < 8; ++i) t += sPart[i];
        atomicAdd(&wsem[p], t);
    }
}

// ---------------- K6: bsem = softmax(wsem / N) ----------------
__global__ void k_bsem(const float* __restrict__ wsem, float* __restrict__ bsem)
{
    if (threadIdx.x == 0 && blockIdx.x == 0) {
        float w[PP];
        for (int p = 0; p < PP; ++p) w[p] = wsem[p] / (float)NN;
        float m = fmaxf(w[0], fmaxf(w[1], w[2]));
        float s = 0.f;
        for (int p = 0; p < PP; ++p) { w[p] = expf(w[p] - m); s += w[p]; }
        for (int p = 0; p < PP; ++p) bsem[p] = w[p] / s;
    }
}

// ---------------- K7: out = sum_p bsem[p] * z_p (z already elu'd) --------
__global__ __launch_bounds__(256) void k_final(
    const float* __restrict__ z, const float* __restrict__ bsem,
    float* __restrict__ out)
{
    const int i = blockIdx.x * 256 + threadIdx.x;
    if (i >= NN * 128) return;
    const float b0 = bsem[0], b1 = bsem[1], b2 = bsem[2];
    const float v0 = z[i];
    const float v1 = z[(size_t)NN * 128 + i];
    const float v2 = z[(size_t)2 * NN * 128 + i];
    out[i] = b0 * v0 + b1 * v1 + b2 * v2;
}

extern "C" void kernel_launch(void* const* d_in, const int* in_sizes, int n_in,
                              void* d_out, int out_size, void* d_ws, size_t ws_size,
                              hipStream_t stream) {
    const float* h      = (const float*)d_in[0];
    const float* c      = (const float*)d_in[1];
    const float* fa_w1  = (const float*)d_in[2];
    const float* fa_b1  = (const float*)d_in[3];
    const float* fa_w2  = (const float*)d_in[4];
    const float* gat_W  = (const float*)d_in[5];
    const float* attn_l = (const float*)d_in[6];
    const float* attn_r = (const float*)d_in[7];
    const float* sa_w1  = (const float*)d_in[8];
    const float* sa_b1  = (const float*)d_in[9];
    const float* sa_w2  = (const float*)d_in[10];
    const int*   src    = (const int*)d_in[11];
    const int*   dst    = (const int*)d_in[12];
    float* out = (float*)d_out;

    float* ws = (float*)d_ws;
    float* x    = ws;                        // 6,400,000 f
    // After k_gat_gemm, the x region is dead; reuse it for the sorted arrays.
    int*   s_src = (int*)x;                  // 1,200,000 i (aliases x)
    float* s_ee  = x + 1200000;              // 4,800,000 f (aliases x, 16B-aligned)
    float* feat = x + 6400000;               // 19,200,000 f
    float* el   = feat + 19200000;           //    600,000 f
    float* er   = el + 600000;               //    600,000 f
    float* z    = er + 600000;               // 19,200,000 f
    int*   row_start = (int*)(z + 19200000); // 3*(NN+1) = 150,003 i
    int*   cursor    = row_start + 150003;   //    150,000 i
    int*   psum      = cursor + 150000;      //  3*NBLK = 588 i
    int*   deg       = psum + 588;           //    150,000 i
    float* wsem      = (float*)(deg + 150000); // 4 f
    float* bsem      = wsem + 4;             // 4 f

    // zero deg + wsem in one contiguous memset (deg..wsem adjacent)
    hipMemsetAsync(deg, 0, (size_t)(150000 + 4) * sizeof(float), stream);

    k_featattn<<<NN / 16, 256, 0, stream>>>(h, c, fa_w1, fa_b1, fa_w2, x);
    k_gat_gemm<<<dim3((NN + 63) / 64, PP), 256, 0, stream>>>(x, gat_W, attn_l, attn_r, feat, el, er);
    k_hist<<<dim3((EE + 255) / 256, PP), 256, 0, stream>>>(dst, deg);
    k_partial<<<dim3(NBLK, PP), 256, 0, stream>>>(deg, psum);
    k_scanpsum<<<PP, 64, 0, stream>>>(psum);
    k_scanfinal<<<dim3(NBLK, PP), 256, 0, stream>>>(deg, psum, row_start, cursor);
    k_scatter<<<dim3((EE + 255) / 256, PP), 256, 0, stream>>>(src, dst, el, er, cursor, s_src, s_ee);
    k_agg<<<dim3((NN + 3) / 4, PP), 256, 0, stream>>>(row_start, s_src, s_ee, feat, z);
    k_sem_score<<<dim3((NN + 63) / 64, PP), 256, 0, stream>>>(z, sa_w1, sa_b1, sa_w2, wsem);
    k_bsem<<<1, 64, 0, stream>>>(wsem, bsem);
    k_final<<<(NN * 128 + 255) / 256, 256, 0, stream>>>(z, bsem, out);
}